// Round 3
// baseline (316.761 us; speedup 1.0000x reference)
//
#include <hip/hip_runtime.h>

// Perceive3D: x (B=4, C=16, D=64, H=64, W=64) fp32, edge-padded 3^3 stencil,
// 4 separable kernels (identity, sobel-W, sobel-H, sobel-D), out (B,4,C,D,H,W).
//
// R3: rolling-plane pipeline along D. Per plane compute once:
//   P = H-smooth of W-diff   (-> sx)
//   Q = H-diff  of W-smooth  (-> sy)
//   R = H-smooth of W-smooth (-> sz)
// then each output d combines 3 rolling planes. 3 loads + 6 shuffles per
// plane instead of 9 loads + 18 shuffles per output point.
// Memory floor: 64 MB in + 268 MB out => ~53 us at 6.3 TB/s.

#define B_ 4
#define C_ 16
#define D_ 64
#define H_ 64
#define W_ 64
#define DCHUNK 8

typedef float float4v __attribute__((ext_vector_type(4)));

struct PQR { float4v P, Q, R, qc; };

__device__ __forceinline__ PQR load_plane(const float* __restrict__ xb,
                                          int z, int hm, int h, int hp,
                                          int quad)
{
    const float* pl = xb + z * (H_ * W_);
    const int rows[3] = { hm, h, hp };
    float4v qmid = {0,0,0,0};
    float4v sw[3], dw[3];
#pragma unroll
    for (int r = 0; r < 3; ++r) {
        float4v v = *(const float4v*)(pl + rows[r] * W_ + 4 * quad);
        float left  = __shfl_up(v.w, 1);
        float right = __shfl_down(v.x, 1);
        if (quad == 0)  left  = v.x;    // w=-1 clamps to w=0
        if (quad == 15) right = v.w;    // w=64 clamps to w=63
        float4v am = { left, v.x, v.y, v.z };   // x[w-1]
        float4v ap = { v.y, v.z, v.w, right };  // x[w+1]
        sw[r] = am + 2.0f * v + ap;
        dw[r] = ap - am;
        if (r == 1) qmid = v;
    }
    PQR o;
    o.P  = dw[0] + 2.0f * dw[1] + dw[2];
    o.Q  = sw[2] - sw[0];
    o.R  = sw[0] + 2.0f * sw[1] + sw[2];
    o.qc = qmid;
    return o;
}

__global__ __launch_bounds__(256) void perceive3d_kernel(
    const float* __restrict__ x, float* __restrict__ out)
{
    const int lane = threadIdx.x;          // 0..63
    const int quad = lane & 15;            // w = 4*quad
    const int hsub = lane >> 4;            // 0..3
    const int h    = blockIdx.x * 16 + threadIdx.y * 4 + hsub;
    const int d0   = blockIdx.y * DCHUNK;
    const int bc   = blockIdx.z;           // b*C + c
    const int b    = bc >> 4;
    const int c    = bc & 15;

    const int hm = (h == 0) ? 0 : h - 1;
    const int hp = (h == H_ - 1) ? H_ - 1 : h + 1;

    const float* xb = x + (size_t)bc * (D_ * H_ * W_);

    PQR s[3];
    s[0] = load_plane(xb, (d0 == 0) ? 0 : d0 - 1, hm, h, hp, quad);  // plane d0-1
    s[1] = load_plane(xb, d0, hm, h, hp, quad);                      // plane d0

    const size_t dhw  = (size_t)D_ * H_ * W_;
    const size_t cdhw = (size_t)C_ * dhw;
    float* o = out + ((size_t)(b * 4) * C_ + c) * dhw
                   + ((size_t)d0 * H_ + h) * W_ + 4 * quad;

#pragma unroll
    for (int t = 0; t < DCHUNK; ++t) {
        int zn = d0 + t + 1;
        if (zn > D_ - 1) zn = D_ - 1;
        s[(t + 2) % 3] = load_plane(xb, zn, hm, h, hp, quad);  // plane d+1

        const PQR& a = s[t % 3];        // plane d-1
        const PQR& m = s[(t + 1) % 3];  // plane d
        const PQR& p = s[(t + 2) % 3];  // plane d+1

        float4v sx = (a.P + 2.0f * m.P + p.P) * (1.0f / 16.0f);
        float4v sy = (a.Q + 2.0f * m.Q + p.Q) * (1.0f / 16.0f);
        float4v sz = (p.R - a.R) * (1.0f / 16.0f);

        float* od = o + (size_t)t * (H_ * W_);
        __builtin_nontemporal_store(m.qc, (float4v*)(od + 0 * cdhw));
        __builtin_nontemporal_store(sx,   (float4v*)(od + 1 * cdhw));
        __builtin_nontemporal_store(sy,   (float4v*)(od + 2 * cdhw));
        __builtin_nontemporal_store(sz,   (float4v*)(od + 3 * cdhw));
    }
}

extern "C" void kernel_launch(void* const* d_in, const int* in_sizes, int n_in,
                              void* d_out, int out_size, void* d_ws, size_t ws_size,
                              hipStream_t stream) {
    (void)in_sizes; (void)n_in; (void)d_ws; (void)ws_size; (void)out_size;
    const float* x = (const float*)d_in[0];
    float* out = (float*)d_out;

    dim3 block(64, 4, 1);                          // wave = 16 w-quads x 4 h
    dim3 grid(H_ / 16, D_ / DCHUNK, B_ * C_);      // 4 x 8 x 64 = 2048 blocks
    perceive3d_kernel<<<grid, block, 0, stream>>>(x, out);
}